// Round 14
// baseline (436.089 us; speedup 1.0000x reference)
//
#include <hip/hip_runtime.h>

typedef unsigned int uint;
typedef unsigned short ushort_t;
typedef unsigned long long u64;
typedef __attribute__((ext_vector_type(4))) float f32x4;
typedef __attribute__((ext_vector_type(8))) __bf16 bf16x8;
typedef __attribute__((ext_vector_type(8))) unsigned short us8;

#define BATCH 65536
#define VEC 512
#define K 1024
#define GAMMA 0.99f
#define EPS 1e-05f
#define SEG 64
#define MARGIN 0.75f

// GEMM geometry: 128x128 tile, 4 waves (2M x 2N), per-wave 64x64, BK=32
#define NKT (VEC / 32)      // 16 K-tiles

// round-to-nearest-even f32 -> bf16
__device__ __forceinline__ ushort_t rtn(float f) {
    uint u = __float_as_uint(f);
    return (ushort_t)((u + 0x7FFFu + ((u >> 16) & 1u)) >> 16);
}

__device__ __forceinline__ void gl16(const void* g, void* l) {
    __builtin_amdgcn_global_load_lds(
        (const __attribute__((address_space(1))) unsigned int*)g,
        (__attribute__((address_space(3))) unsigned int*)l, 16, 0, 0);
}

__device__ __forceinline__ float dec_key(uint e) {
    uint b = (e & 0x80000000u) ? (e & 0x7FFFFFFFu) : ~e;
    return __uint_as_float(b);
}

// ---- pack w (bf16-rtn B granules, BN=128) + wT + w2 partials + inits ----
// grid 128 blocks (gx 8 x ks 16) x 256 thr; granule o in [0,512):
//   ct=o>>6, lane=o&63; col=gx*128+ct*16+(lane&15); k=ks*32+(lane>>4)*8+j
__global__ void k_pack_w(const float* __restrict__ w, us8* __restrict__ wpk,
                         float* __restrict__ wT, float* __restrict__ w2p,
                         int* __restrict__ cc /* counts|cursor: 2048 ints */) {
    __shared__ float lds[32][129];
    const int g = blockIdx.x;
    const int gx = g >> 4, ks = g & 15;
    const int t = threadIdx.x;

#pragma unroll
    for (int i = 0; i < 16; ++i) {
        const int idx = i * 256 + t;
        const int row = idx >> 7, col = idx & 127;
        lds[row][col] = w[(size_t)(ks * 32 + row) * K + gx * 128 + col];
    }
    __syncthreads();

    // w2 partial for this ks-slice (one writer per entry)
    if (t < 128) {
        float s = 0.f;
#pragma unroll
        for (int r = 0; r < 32; ++r) { float f = lds[r][t]; s += f * f; }
        w2p[ks * K + gx * 128 + t] = s;
    }

    // bf16 granules
#pragma unroll
    for (int i = 0; i < 2; ++i) {
        const int o = i * 256 + t;
        const int lane = o & 63, ct = o >> 6;
        const int cl = ct * 16 + (lane & 15);
        const int r0 = (lane >> 4) * 8;
        us8 v;
#pragma unroll
        for (int j = 0; j < 8; ++j) v[j] = rtn(lds[r0 + j][cl]);
        wpk[(size_t)g * 512 + o] = v;
    }

    // wT: (K, VEC) f32 transpose for coalesced per-col reads in recheck
    {
        const int c = t & 127;
        const int rb = (t >> 7) * 16;
#pragma unroll
        for (int rr = 0; rr < 4; ++rr) {
            f32x4 v = {lds[rb + rr * 4 + 0][c], lds[rb + rr * 4 + 1][c],
                       lds[rb + rr * 4 + 2][c], lds[rb + rr * 4 + 3][c]};
            *(f32x4*)&wT[(size_t)(gx * 128 + c) * VEC + ks * 32 + rb + rr * 4] = v;
        }
    }

    if (g < 8) cc[g * 256 + t] = 0;
}

// ---- main: 128x128 single-bf16 MFMA distance GEMM, top-2 per row per slot ----
// 4096 blocks x 256 thr; 4 blocks/CU (32KB LDS, <=128 VGPR incl. acc).
// 4 independent barrier domains per CU hide each other's staging stalls.
__launch_bounds__(256, 4)
__global__ void k_gemm(const float* __restrict__ x, const us8* __restrict__ wpk,
                       const float* __restrict__ w2p,
                       u64* __restrict__ keysA, u64* __restrict__ keysB) {
    __shared__ us8 a_lds[2][512];   // 128 rows x 32k bf16, 8KB/buf
    __shared__ us8 b_lds[2][512];   // 128 cols x 32k bf16, 8KB/buf

    const int blk = blockIdx.x;
    // XCD-chunked bijection (4096 % 8 == 0): XCD c owns gy [c*64, c*64+64),
    // the 8 gx of each gy adjacent -> A-tile L2 reuse.
    const int ord = blk >> 3;
    const int gx = ord & 7;
    const int gy = (blk & 7) * 64 + (ord >> 3);
    const int t = threadIdx.x;
    const int lane = t & 63;
    const int wv = t >> 6;       // 0..3
    const int wm = wv >> 1;      // 0..1 (64 rows)
    const int wn = wv & 1;       // 0..1 (64 cols)

    const us8* bsrc = wpk + (size_t)gx * (NKT * 512);

    // A staging: thread t owns granules {t, t+256}: slab=(t>>6)(+4), lane=t&63
    const int al = t & 63;
    const float* xp0 = x + (size_t)(gy * 128 + (t >> 6) * 16 + (al & 15)) * VEC + (al >> 4) * 8;
    const float* xp1 = xp0 + (size_t)64 * VEC;
    f32x4 av0, av1, av2, av3;
    auto aload = [&](int kt) {
        const float* p0 = xp0 + kt * 32;
        av0 = *(const f32x4*)p0;
        av1 = *(const f32x4*)(p0 + 4);
        const float* p1 = xp1 + kt * 32;
        av2 = *(const f32x4*)p1;
        av3 = *(const f32x4*)(p1 + 4);
    };
    auto awrite = [&](int buf) {
        us8 h0, h1;
#pragma unroll
        for (int j = 0; j < 4; ++j) {
            h0[j] = rtn(av0[j]); h0[4 + j] = rtn(av1[j]);
            h1[j] = rtn(av2[j]); h1[4 + j] = rtn(av3[j]);
        }
        a_lds[buf][t] = h0;
        a_lds[buf][256 + t] = h1;
    };
    auto bstage = [&](int buf, int kt) {
        const us8* sb = bsrc + (size_t)kt * 512;
        gl16(sb + t, &b_lds[buf][t]);
        gl16(sb + 256 + t, &b_lds[buf][256 + t]);
    };

    f32x4 acc[4][4];
#pragma unroll
    for (int i = 0; i < 4; ++i)
#pragma unroll
        for (int j = 0; j < 4; ++j) acc[i][j] = (f32x4){0.f, 0.f, 0.f, 0.f};

    aload(0);
    bstage(0, 0);
    awrite(0);
    __syncthreads();

    for (int tk = 0; tk < NKT; ++tk) {
        const int buf = tk & 1;
        const bool nx = (tk + 1 < NKT);
        if (nx) {
            aload(tk + 1);
            bstage(buf ^ 1, tk + 1);
        }
        bf16x8 bh[4];
#pragma unroll
        for (int ct = 0; ct < 4; ++ct)
            bh[ct] = __builtin_bit_cast(bf16x8, b_lds[buf][(wn * 4 + ct) * 64 + lane]);
#pragma unroll
        for (int rt = 0; rt < 4; ++rt) {
            bf16x8 ah = __builtin_bit_cast(bf16x8, a_lds[buf][(wm * 4 + rt) * 64 + lane]);
#pragma unroll
            for (int ct = 0; ct < 4; ++ct)
                acc[rt][ct] = __builtin_amdgcn_mfma_f32_16x16x32_bf16(ah, bh[ct], acc[rt][ct], 0, 0, 0);
        }
        if (nx) awrite(buf ^ 1);
        __syncthreads();
    }

    // epilogue: dist = w2 - 2*dot; per-row TOP-2 over this wave's 64 cols;
    // plain store to slot (gx*2+wn) -- no atomics, deterministic.
    const int col_base = gx * 128 + wn * 64;
    float w2c[4];
#pragma unroll
    for (int ct = 0; ct < 4; ++ct) {
        const int col = col_base + ct * 16 + (lane & 15);
        float s = 0.f;
#pragma unroll
        for (int p = 0; p < 16; ++p) s += w2p[p * K + col];
        w2c[ct] = s;
    }
    const int slot = gx * 2 + wn;

#pragma unroll
    for (int rt = 0; rt < 4; ++rt) {
#pragma unroll
        for (int reg = 0; reg < 4; ++reg) {
            u64 k1 = ~0ull, k2 = ~0ull;
#pragma unroll
            for (int ct = 0; ct < 4; ++ct) {
                float dist = w2c[ct] - 2.0f * acc[rt][ct][reg];
                uint su = __float_as_uint(dist);
                su = (su & 0x80000000u) ? ~su : (su | 0x80000000u);
                const u64 key = ((u64)su << 32) | (uint)(col_base + ct * 16 + (lane & 15));
                if (key < k1) { k2 = k1; k1 = key; }
                else if (key < k2) { k2 = key; }
            }
#pragma unroll
            for (int m = 1; m < 16; m <<= 1) {
                u64 o1 = __shfl_xor((unsigned long long)k1, m);
                u64 o2 = __shfl_xor((unsigned long long)k2, m);
                u64 lo = k1 < o1 ? k1 : o1;
                u64 hi = k1 < o1 ? o1 : k1;
                u64 mn2 = k2 < o2 ? k2 : o2;
                k1 = lo;
                k2 = hi < mn2 ? hi : mn2;
            }
            if ((lane & 15) == 0) {
                const int row = gy * 128 + wm * 64 + rt * 16 + (lane >> 4) * 4 + reg;
                keysA[(size_t)slot * BATCH + row] = k1;
                keysB[(size_t)slot * BATCH + row] = k2;
            }
        }
    }
}

// ---- verify + fused recheck: merge 16 slots -> top-2; margin test; exact
//      recheck of marginal rows via per-block LDS list (wave-cooperative) ----
__global__ void k_verify(const u64* __restrict__ keysA, const u64* __restrict__ keysB,
                         const float* __restrict__ x, const float* __restrict__ wT,
                         const float* __restrict__ w2p,
                         int* __restrict__ am, int* __restrict__ counts,
                         float* __restrict__ esum) {
    __shared__ int lrow[256];
    __shared__ int lcc[256];
    __shared__ int lcnt;
    const int t = threadIdx.x;
    const int r = blockIdx.x * 256 + t;
    const int lane = t & 63;

    if (t == 0) lcnt = 0;
    __syncthreads();

    // zero esum (2MB / 65536 threads = 8 floats)
    f32x4 z = {0.f, 0.f, 0.f, 0.f};
    ((f32x4*)esum)[r * 2] = z;
    ((f32x4*)esum)[r * 2 + 1] = z;

    u64 m1 = ~0ull, s = ~0ull;
    int i1 = 0;
#pragma unroll
    for (int i = 0; i < 16; ++i) {
        u64 a = keysA[(size_t)i * BATCH + r];
        if (a < m1) { s = m1; m1 = a; i1 = i; }
        else if (a < s) s = a;
    }
    u64 b = keysB[(size_t)i1 * BATCH + r];
    u64 m2 = s < b ? s : b;

    const float d1 = dec_key((uint)(m1 >> 32));
    const float d2 = dec_key((uint)(m2 >> 32));
    const int c1 = (int)(uint)m1 & 1023;
    const int c2 = (int)(uint)m2 & 1023;

    if (d2 - d1 > MARGIN) {
        am[r] = c1;
        atomicAdd(&counts[c1], 1);
    } else {
        int p = atomicAdd(&lcnt, 1);
        lrow[p] = r;
        lcc[p] = (c1 << 10) | c2;
    }
    __syncthreads();

    // wave-cooperative exact recheck of this block's marginal rows
    const int n = lcnt;
    for (int idx = t >> 6; idx < n; idx += 4) {
        const int r2 = lrow[idx];
        const int cc1 = lcc[idx] >> 10;
        const int cc2 = lcc[idx] & 1023;
        const f32x4 x0 = *(const f32x4*)&x[(size_t)r2 * VEC + lane * 8];
        const f32x4 x1 = *(const f32x4*)&x[(size_t)r2 * VEC + lane * 8 + 4];
        float d[2];
        const int cand[2] = {cc1, cc2};
#pragma unroll
        for (int j = 0; j < 2; ++j) {
            const int c = cand[j];
            const f32x4 w0 = *(const f32x4*)&wT[(size_t)c * VEC + lane * 8];
            const f32x4 w1 = *(const f32x4*)&wT[(size_t)c * VEC + lane * 8 + 4];
            float p = x0[0] * w0[0] + x0[1] * w0[1] + x0[2] * w0[2] + x0[3] * w0[3]
                    + x1[0] * w1[0] + x1[1] * w1[1] + x1[2] * w1[2] + x1[3] * w1[3];
#pragma unroll
            for (int m = 1; m < 64; m <<= 1) p += __shfl_xor(p, m);
            float w2 = 0.f;
#pragma unroll
            for (int q = 0; q < 16; ++q) w2 += w2p[q * K + c];
            d[j] = w2 - 2.0f * p;
        }
        const int win = (d[0] < d[1] || (d[0] == d[1] && cc1 < cc2)) ? cc1 : cc2;
        if (lane == 0) {
            am[r2] = win;
            atomicAdd(&counts[win], 1);
        }
    }
}

// ---- scan of counts -> offsets; EMA cluster sizes -> cs (wave-shuffle) ----
__global__ void k_scan(const int* __restrict__ counts,
                       const float* __restrict__ cluster_size,
                       int* __restrict__ offsets, float* __restrict__ cs) {
    __shared__ int wsum[16];
    __shared__ float fw[16];
    const int t = threadIdx.x;           // 0..1023
    const int lane = t & 63, wid = t >> 6;
    const int c = counts[t];

    int s = c;
#pragma unroll
    for (int d = 1; d < 64; d <<= 1) {
        int o = __shfl_up(s, d);
        if (lane >= d) s += o;
    }
    float ncs = GAMMA * cluster_size[t] + (1.0f - GAMMA) * ((c == 0) ? 1.0f : (float)c);
    float fs = ncs;
#pragma unroll
    for (int d = 32; d > 0; d >>= 1) fs += __shfl_xor(fs, d);

    if (lane == 63) wsum[wid] = s;
    if (lane == 0) fw[wid] = fs;
    __syncthreads();
    if (wid == 0 && lane < 16) {
        int v = wsum[lane];
#pragma unroll
        for (int d = 1; d < 16; d <<= 1) {
            int o = __shfl_up(v, d);
            if (lane >= d) v += o;
        }
        wsum[lane] = v;
    }
    __syncthreads();
    const int base = wid ? wsum[wid - 1] : 0;
    offsets[t] = base + s - c;

    float n = 0.f;
#pragma unroll
    for (int i = 0; i < 16; ++i) n += fw[i];
    cs[t] = (ncs + EPS) / (n + (float)K * EPS) * n;
}

// ---- counting-sort scatter ----
__global__ void k_scatter(const int* __restrict__ am, const int* __restrict__ offsets,
                          int* __restrict__ cursor, int* __restrict__ sorted,
                          int* __restrict__ sortedk) {
    const int b = blockIdx.x * blockDim.x + threadIdx.x;
    const int k = am[b];
    const int pos = atomicAdd(&cursor[k], 1);
    sorted[offsets[k] + pos] = b;
    sortedk[offsets[k] + pos] = k;
}

// ---- balanced segmented reduction: 64 sorted rows per block ----
__launch_bounds__(512)
__global__ void k_segred(const float* __restrict__ x, const int* __restrict__ sorted,
                         const int* __restrict__ sortedk, float* __restrict__ esum) {
    __shared__ int srow[SEG];
    __shared__ int skid[SEG];
    const int b = blockIdx.x;
    const int t = threadIdx.x;
    if (t < SEG) {
        srow[t] = sorted[b * SEG + t];
        skid[t] = sortedk[b * SEG + t];
    }
    __syncthreads();

    float a = 0.f;
    int cur = skid[0];
#pragma unroll 8
    for (int i = 0; i < SEG; ++i) {
        const int k = skid[i];
        if (k != cur) {
            atomicAdd(&esum[(size_t)cur * VEC + t], a);
            a = 0.f;
            cur = k;
        }
        a += x[(size_t)srow[i] * VEC + t];
    }
    atomicAdd(&esum[(size_t)cur * VEC + t], a);
}

// ---- finalize: transpose esum (K,VEC)->(VEC,K), EMA + normalize ----
__launch_bounds__(256)
__global__ void k_finalize(const float* __restrict__ esum, const float* __restrict__ embed_avg,
                           const float* __restrict__ cs, float* __restrict__ out) {
    __shared__ float tile[64][65];
    const int k0 = blockIdx.x * 64;
    const int v0 = blockIdx.y * 64;
    const int c = threadIdx.x & 63;
    const int r0 = threadIdx.x >> 6;
#pragma unroll
    for (int j = 0; j < 16; ++j) {
        const int r = r0 + j * 4;
        tile[r][c] = esum[(size_t)(k0 + r) * VEC + v0 + c];
    }
    __syncthreads();
    const float csk = cs[k0 + c];
#pragma unroll
    for (int j = 0; j < 16; ++j) {
        const int r = r0 + j * 4;
        const size_t o = (size_t)(v0 + r) * K + k0 + c;
        out[o] = (GAMMA * embed_avg[o] + (1.0f - GAMMA) * tile[c][r]) / csk;
    }
}

extern "C" void kernel_launch(void* const* d_in, const int* in_sizes, int n_in,
                              void* d_out, int out_size, void* d_ws, size_t ws_size,
                              hipStream_t stream) {
    const float* x            = (const float*)d_in[0];   // (BATCH, VEC)
    const float* w            = (const float*)d_in[1];   // (VEC, K)
    const float* cluster_size = (const float*)d_in[2];   // (K,)
    const float* embed_avg    = (const float*)d_in[3];   // (VEC, K)
    float* out = (float*)d_out;                          // (VEC, K)

    // ws layout (~22 MB)
    u64*   keysA   = (u64*)d_ws;                          // 16 x BATCH
    u64*   keysB   = keysA + (size_t)16 * BATCH;          // 16 x BATCH
    int*   am      = (int*)(keysB + (size_t)16 * BATCH);  // BATCH
    float* w2p     = (float*)(am + BATCH);                // 16 x K
    float* cs      = w2p + 16 * K;                        // K
    int*   cc      = (int*)(cs + K);                      // counts K | cursor K
    int*   counts  = cc;
    int*   cursor  = cc + K;
    int*   offsets = cc + 2 * K;                          // K
    int*   sorted  = offsets + K;                         // BATCH
    int*   sortedk = sorted + BATCH;                      // BATCH
    float* esum    = (float*)(sortedk + BATCH);           // (K, VEC), 2 MB
    us8*   wpk     = (us8*)(esum + (size_t)K * VEC);      // 1 MB (128 groups x 512)
    float* wT      = (float*)(wpk + (size_t)128 * 512);   // (K, VEC), 2 MB

    k_pack_w<<<128, 256, 0, stream>>>(w, wpk, wT, w2p, cc);
    k_gemm<<<4096, 256, 0, stream>>>(x, wpk, w2p, keysA, keysB);
    k_verify<<<BATCH / 256, 256, 0, stream>>>(keysA, keysB, x, wT, w2p, am, counts, esum);
    k_scan<<<1, K, 0, stream>>>(counts, cluster_size, offsets, cs);
    k_scatter<<<BATCH / 256, 256, 0, stream>>>(am, offsets, cursor, sorted, sortedk);
    k_segred<<<BATCH / SEG, 512, 0, stream>>>(x, sorted, sortedk, esum);
    k_finalize<<<dim3(K / 64, VEC / 64), 256, 0, stream>>>(esum, embed_avg, cs, out);
}

// Round 15
// 413.824 us; speedup vs baseline: 1.0538x; 1.0538x over previous
//
#include <hip/hip_runtime.h>

typedef unsigned int uint;
typedef unsigned short ushort_t;
typedef unsigned long long u64;
typedef __attribute__((ext_vector_type(4))) float f32x4;
typedef __attribute__((ext_vector_type(8))) __bf16 bf16x8;
typedef __attribute__((ext_vector_type(8))) unsigned short us8;

#define BATCH 65536
#define VEC 512
#define K 1024
#define GAMMA 0.99f
#define EPS 1e-05f
#define SEG 64
#define MARGIN 0.75f

// GEMM geometry: 256x256 tile, BK=64, 8 waves (2M x 4N), per-wave 128x64
#define NKT (VEC / 64)      // 8 K-tiles
#define TG 2048             // granules per K-tile per operand

// round-to-nearest-even f32 -> bf16
__device__ __forceinline__ ushort_t rtn(float f) {
    uint u = __float_as_uint(f);
    return (ushort_t)((u + 0x7FFFu + ((u >> 16) & 1u)) >> 16);
}

__device__ __forceinline__ void gl16(const void* g, void* l) {
    __builtin_amdgcn_global_load_lds(
        (const __attribute__((address_space(1))) unsigned int*)g,
        (__attribute__((address_space(3))) unsigned int*)l, 16, 0, 0);
}

__device__ __forceinline__ float dec_key(uint e) {
    uint b = (e & 0x80000000u) ? (e & 0x7FFFFFFFu) : ~e;
    return __uint_as_float(b);
}

#define BC8(p) __builtin_bit_cast(bf16x8, (p))

// ---- pack w into B granules [gx 4][kt 8][g 2048] + wT + w2 partials + inits --
// granule g = ct*128 + ksub*64 + lane: col = gx*256+ct*16+(lane&15),
// k = kt*64 + ksub*32 + (lane>>4)*8 + j
__global__ void k_pack_w(const float* __restrict__ w, us8* __restrict__ wpk,
                         float* __restrict__ wT, float* __restrict__ w2p,
                         int* __restrict__ cc /* counts|cursor|listcnt */) {
    __shared__ float lds[32][257];
    const int g = blockIdx.x;            // 32 blocks: gx*8 + kt
    const int gx = g >> 3, kt = g & 7;
    const int t = threadIdx.x;

    float s = 0.f;
#pragma unroll
    for (int ih = 0; ih < 2; ++ih) {
        __syncthreads();
#pragma unroll
        for (int r = 0; r < 32; ++r)
            lds[r][t] = w[(size_t)(kt * 64 + ih * 32 + r) * K + gx * 256 + t];
        __syncthreads();

#pragma unroll
        for (int r = 0; r < 32; ++r) { float f = lds[r][t]; s += f * f; }

#pragma unroll
        for (int i = 0; i < 4; ++i) {
            const int c = i * 256 + t;               // 0..1023
            const int ct = c >> 6, lane = c & 63;
            const int cl = ct * 16 + (lane & 15);
            const int r0 = (lane >> 4) * 8;
            us8 v;
#pragma unroll
            for (int j = 0; j < 8; ++j) v[j] = rtn(lds[r0 + j][cl]);
            wpk[(size_t)g * TG + ct * 128 + ih * 64 + lane] = v;
        }

#pragma unroll
        for (int rr = 0; rr < 8; ++rr) {
            f32x4 v = {lds[rr * 4 + 0][t], lds[rr * 4 + 1][t],
                       lds[rr * 4 + 2][t], lds[rr * 4 + 3][t]};
            *(f32x4*)&wT[(size_t)(gx * 256 + t) * VEC + kt * 64 + ih * 32 + rr * 4] = v;
        }
    }
    w2p[kt * K + gx * 256 + t] = s;

    if (g < 8) cc[g * 256 + t] = 0;
    if (g == 8 && t == 0) cc[2048] = 0;
}

// ---- pack x into A granules [gy 256][kt 8][g 2048] (streaming cast) ----
// granule g = slab*128 + ksub*64 + lane: row = gy*256+slab*16+(lane&15),
// k = kt*64 + ksub*32 + (lane>>4)*8 + j. A wave's 64 loads cover 16 full
// 128B lines (lanes l, l+16, l+32, l+48 share a row) -> no over-fetch.
__global__ void k_pack_x(const float* __restrict__ x, us8* __restrict__ xpk) {
    const int blk = blockIdx.x;          // 2048: gy*8 + kt
    const int gy = blk >> 3, kt = blk & 7;
    const int t = threadIdx.x;
#pragma unroll
    for (int i = 0; i < 8; ++i) {
        const int g = i * 256 + t;
        const int slab = g >> 7, ksub = (g >> 6) & 1, lane = g & 63;
        const int row = gy * 256 + slab * 16 + (lane & 15);
        const int k = kt * 64 + ksub * 32 + ((lane >> 4) << 3);
        const f32x4 q0 = *(const f32x4*)&x[(size_t)row * VEC + k];
        const f32x4 q1 = *(const f32x4*)&x[(size_t)row * VEC + k + 4];
        us8 v;
#pragma unroll
        for (int j = 0; j < 4; ++j) { v[j] = rtn(q0[j]); v[4 + j] = rtn(q1[j]); }
        xpk[(size_t)blk * TG + g] = v;
    }
}

// ---- main: 256x256 BK=64 8-phase MFMA distance GEMM, top-2 per slot ----
// 1024 blocks x 512 thr; 1 block/CU (128KB LDS); counted vmcnt; 4 phases/kt.
__launch_bounds__(512, 2)
__global__ void k_gemm(const us8* __restrict__ xpk, const us8* __restrict__ wpk,
                       const float* __restrict__ w2p,
                       u64* __restrict__ keysA, u64* __restrict__ keysB) {
    __shared__ us8 lds[2][2 * TG];   // [0..2047]=A, [2048..4095]=B; 128 KB

    const int blk = blockIdx.x;
    // XCD-chunked bijection (1024 % 8 == 0)
    const int ord = blk >> 3;
    const int gy = (blk & 7) * 32 + (ord >> 2);
    const int gx = ord & 3;
    const int t = threadIdx.x;
    const int lane = t & 63;
    const int wv = t >> 6;
    const int wm = wv >> 2;      // 0..1 (128 rows)
    const int wn = wv & 3;       // 0..3 (64 cols)

    const us8* asrc = xpk + (size_t)gy * (NKT * TG);
    const us8* bsrc = wpk + (size_t)gx * (NKT * TG);

    auto stage = [&](int slot, int kt) {
        const us8* sa = asrc + (size_t)kt * TG;
        const us8* sb = bsrc + (size_t)kt * TG;
#pragma unroll
        for (int i = 0; i < 4; ++i) gl16(sa + i * 512 + t, &lds[slot][i * 512 + t]);
#pragma unroll
        for (int i = 0; i < 4; ++i) gl16(sb + i * 512 + t, &lds[slot][TG + i * 512 + t]);
    };

    f32x4 acc[8][4];
#pragma unroll
    for (int i = 0; i < 8; ++i)
#pragma unroll
        for (int j = 0; j < 4; ++j) acc[i][j] = (f32x4){0.f, 0.f, 0.f, 0.f};

    stage(0, 0);
    stage(1, 1);

    for (int kt = 0; kt < NKT; ++kt) {
        const int buf = kt & 1;
        if (kt >= 1 && kt + 1 < NKT) {
            stage(buf ^ 1, kt + 1);      // slot buf^1 freed by kt-1's last barrier
            asm volatile("s_waitcnt vmcnt(8)" ::: "memory");  // tile kt landed
        } else if (kt == 0) {
            asm volatile("s_waitcnt vmcnt(8)" ::: "memory");
        } else {                          // kt == NKT-1
            asm volatile("s_waitcnt vmcnt(0)" ::: "memory");
        }
        __builtin_amdgcn_s_barrier();     // all waves' staging of tile kt visible

        const us8* A = &lds[buf][0];
        const us8* B = &lds[buf][TG];
        bf16x8 ah[8], b0, b1;

        // ---- phase 0: ksub0, ct {0,1} ----
#pragma unroll
        for (int rt = 0; rt < 8; ++rt) ah[rt] = BC8(A[(wm * 8 + rt) * 128 + lane]);
        b0 = BC8(B[(wn * 4 + 0) * 128 + lane]);
        b1 = BC8(B[(wn * 4 + 1) * 128 + lane]);
        __builtin_amdgcn_s_barrier();
        asm volatile("s_waitcnt lgkmcnt(0)" ::: "memory");
        __builtin_amdgcn_sched_barrier(0);
        __builtin_amdgcn_s_setprio(1);
#pragma unroll
        for (int rt = 0; rt < 8; ++rt) {
            acc[rt][0] = __builtin_amdgcn_mfma_f32_16x16x32_bf16(ah[rt], b0, acc[rt][0], 0, 0, 0);
            acc[rt][1] = __builtin_amdgcn_mfma_f32_16x16x32_bf16(ah[rt], b1, acc[rt][1], 0, 0, 0);
        }
        __builtin_amdgcn_s_setprio(0);
        __builtin_amdgcn_s_barrier();

        // ---- phase 1: ksub0, ct {2,3} ----
        b0 = BC8(B[(wn * 4 + 2) * 128 + lane]);
        b1 = BC8(B[(wn * 4 + 3) * 128 + lane]);
        __builtin_amdgcn_s_barrier();
        asm volatile("s_waitcnt lgkmcnt(0)" ::: "memory");
        __builtin_amdgcn_sched_barrier(0);
        __builtin_amdgcn_s_setprio(1);
#pragma unroll
        for (int rt = 0; rt < 8; ++rt) {
            acc[rt][2] = __builtin_amdgcn_mfma_f32_16x16x32_bf16(ah[rt], b0, acc[rt][2], 0, 0, 0);
            acc[rt][3] = __builtin_amdgcn_mfma_f32_16x16x32_bf16(ah[rt], b1, acc[rt][3], 0, 0, 0);
        }
        __builtin_amdgcn_s_setprio(0);
        __builtin_amdgcn_s_barrier();

        // ---- phase 2: ksub1, ct {0,1} ----
#pragma unroll
        for (int rt = 0; rt < 8; ++rt) ah[rt] = BC8(A[(wm * 8 + rt) * 128 + 64 + lane]);
        b0 = BC8(B[(wn * 4 + 0) * 128 + 64 + lane]);
        b1 = BC8(B[(wn * 4 + 1) * 128 + 64 + lane]);
        __builtin_amdgcn_s_barrier();
        asm volatile("s_waitcnt lgkmcnt(0)" ::: "memory");
        __builtin_amdgcn_sched_barrier(0);
        __builtin_amdgcn_s_setprio(1);
#pragma unroll
        for (int rt = 0; rt < 8; ++rt) {
            acc[rt][0] = __builtin_amdgcn_mfma_f32_16x16x32_bf16(ah[rt], b0, acc[rt][0], 0, 0, 0);
            acc[rt][1] = __builtin_amdgcn_mfma_f32_16x16x32_bf16(ah[rt], b1, acc[rt][1], 0, 0, 0);
        }
        __builtin_amdgcn_s_setprio(0);
        __builtin_amdgcn_s_barrier();

        // ---- phase 3: ksub1, ct {2,3} ----
        b0 = BC8(B[(wn * 4 + 2) * 128 + 64 + lane]);
        b1 = BC8(B[(wn * 4 + 3) * 128 + 64 + lane]);
        __builtin_amdgcn_s_barrier();
        asm volatile("s_waitcnt lgkmcnt(0)" ::: "memory");
        __builtin_amdgcn_sched_barrier(0);
        __builtin_amdgcn_s_setprio(1);
#pragma unroll
        for (int rt = 0; rt < 8; ++rt) {
            acc[rt][2] = __builtin_amdgcn_mfma_f32_16x16x32_bf16(ah[rt], b0, acc[rt][2], 0, 0, 0);
            acc[rt][3] = __builtin_amdgcn_mfma_f32_16x16x32_bf16(ah[rt], b1, acc[rt][3], 0, 0, 0);
        }
        __builtin_amdgcn_s_setprio(0);
        __builtin_amdgcn_s_barrier();
    }

    // epilogue: dist = w2 - 2*dot; per-row TOP-2 over wave's 64 cols; slot store
    const int col_base = gx * 256 + wn * 64;
    float w2c[4];
#pragma unroll
    for (int ct = 0; ct < 4; ++ct) {
        const int col = col_base + ct * 16 + (lane & 15);
        float s = 0.f;
#pragma unroll
        for (int p = 0; p < 8; ++p) s += w2p[p * K + col];
        w2c[ct] = s;
    }
    const int slot = gx * 4 + wn;

#pragma unroll
    for (int rt = 0; rt < 8; ++rt) {
#pragma unroll
        for (int reg = 0; reg < 4; ++reg) {
            u64 k1 = ~0ull, k2 = ~0ull;
#pragma unroll
            for (int ct = 0; ct < 4; ++ct) {
                float dist = w2c[ct] - 2.0f * acc[rt][ct][reg];
                uint su = __float_as_uint(dist);
                su = (su & 0x80000000u) ? ~su : (su | 0x80000000u);
                const u64 key = ((u64)su << 32) | (uint)(col_base + ct * 16 + (lane & 15));
                if (key < k1) { k2 = k1; k1 = key; }
                else if (key < k2) { k2 = key; }
            }
#pragma unroll
            for (int m = 1; m < 16; m <<= 1) {
                u64 o1 = __shfl_xor((unsigned long long)k1, m);
                u64 o2 = __shfl_xor((unsigned long long)k2, m);
                u64 lo = k1 < o1 ? k1 : o1;
                u64 hi = k1 < o1 ? o1 : k1;
                u64 mn2 = k2 < o2 ? k2 : o2;
                k1 = lo;
                k2 = hi < mn2 ? hi : mn2;
            }
            if ((lane & 15) == 0) {
                const int row = gy * 256 + wm * 128 + rt * 16 + (lane >> 4) * 4 + reg;
                keysA[(size_t)slot * BATCH + row] = k1;
                keysB[(size_t)slot * BATCH + row] = k2;
            }
        }
    }
}

// ---- verify: merge 16 slots/row -> global top-2; margin test; hist; list ----
__global__ void k_verify(const u64* __restrict__ keysA, const u64* __restrict__ keysB,
                         int* __restrict__ am, int* __restrict__ counts,
                         u64* __restrict__ list, int* __restrict__ listcnt,
                         float* __restrict__ esum) {
    const int r = blockIdx.x * 256 + threadIdx.x;
    f32x4 z = {0.f, 0.f, 0.f, 0.f};
    ((f32x4*)esum)[r * 2] = z;
    ((f32x4*)esum)[r * 2 + 1] = z;

    u64 m1 = ~0ull, s = ~0ull;
    int i1 = 0;
#pragma unroll
    for (int i = 0; i < 16; ++i) {
        u64 a = keysA[(size_t)i * BATCH + r];
        if (a < m1) { s = m1; m1 = a; i1 = i; }
        else if (a < s) s = a;
    }
    u64 b = keysB[(size_t)i1 * BATCH + r];
    u64 m2 = s < b ? s : b;

    const float d1 = dec_key((uint)(m1 >> 32));
    const float d2 = dec_key((uint)(m2 >> 32));
    const int c1 = (int)(uint)m1 & 1023;
    const int c2 = (int)(uint)m2 & 1023;

    if (d2 - d1 > MARGIN) {
        am[r] = c1;
        atomicAdd(&counts[c1], 1);
    } else {
        int p = atomicAdd(listcnt, 1);
        list[p] = ((u64)(uint)r << 32) | ((uint)c1 << 10) | (uint)c2;
    }
}

// ---- recheck: exact f32 distance for the 2 candidates of marginal rows ----
__launch_bounds__(256)
__global__ void k_recheck(const float* __restrict__ x, const float* __restrict__ wT,
                          const float* __restrict__ w2p, const u64* __restrict__ list,
                          const int* __restrict__ listcnt, int* __restrict__ am,
                          int* __restrict__ counts) {
    const int gwid = (blockIdx.x * 256 + threadIdx.x) >> 6;   // 1024 waves
    const int lane = threadIdx.x & 63;
    const int n = *listcnt;
    for (int idx = gwid; idx < n; idx += 1024) {
        const u64 e = list[idx];
        const int r = (int)(e >> 32);
        const int c1 = (int)((e >> 10) & 1023);
        const int c2 = (int)(e & 1023);
        const f32x4 x0 = *(const f32x4*)&x[(size_t)r * VEC + lane * 8];
        const f32x4 x1 = *(const f32x4*)&x[(size_t)r * VEC + lane * 8 + 4];
        float d[2];
        const int cc2[2] = {c1, c2};
#pragma unroll
        for (int j = 0; j < 2; ++j) {
            const int c = cc2[j];
            const f32x4 w0 = *(const f32x4*)&wT[(size_t)c * VEC + lane * 8];
            const f32x4 w1 = *(const f32x4*)&wT[(size_t)c * VEC + lane * 8 + 4];
            float p = x0[0] * w0[0] + x0[1] * w0[1] + x0[2] * w0[2] + x0[3] * w0[3]
                    + x1[0] * w1[0] + x1[1] * w1[1] + x1[2] * w1[2] + x1[3] * w1[3];
#pragma unroll
            for (int m = 1; m < 64; m <<= 1) p += __shfl_xor(p, m);
            float w2 = 0.f;
#pragma unroll
            for (int q = 0; q < 8; ++q) w2 += w2p[q * K + c];
            d[j] = w2 - 2.0f * p;
        }
        const int win = (d[0] < d[1] || (d[0] == d[1] && c1 < c2)) ? c1 : c2;
        if (lane == 0) {
            am[r] = win;
            atomicAdd(&counts[win], 1);
        }
    }
}

// ---- scan of counts -> offsets; EMA cluster sizes -> cs (wave-shuffle) ----
__global__ void k_scan(const int* __restrict__ counts,
                       const float* __restrict__ cluster_size,
                       int* __restrict__ offsets, float* __restrict__ cs) {
    __shared__ int wsum[16];
    __shared__ float fw[16];
    const int t = threadIdx.x;           // 0..1023
    const int lane = t & 63, wid = t >> 6;
    const int c = counts[t];

    int s = c;
#pragma unroll
    for (int d = 1; d < 64; d <<= 1) {
        int o = __shfl_up(s, d);
        if (lane >= d) s += o;
    }
    float ncs = GAMMA * cluster_size[t] + (1.0f - GAMMA) * ((c == 0) ? 1.0f : (float)c);
    float fs = ncs;
#pragma unroll
    for (int d = 32; d > 0; d >>= 1) fs += __shfl_xor(fs, d);

    if (lane == 63) wsum[wid] = s;
    if (lane == 0) fw[wid] = fs;
    __syncthreads();
    if (wid == 0 && lane < 16) {
        int v = wsum[lane];
#pragma unroll
        for (int d = 1; d < 16; d <<= 1) {
            int o = __shfl_up(v, d);
            if (lane >= d) v += o;
        }
        wsum[lane] = v;
    }
    __syncthreads();
    const int base = wid ? wsum[wid - 1] : 0;
    offsets[t] = base + s - c;

    float n = 0.f;
#pragma unroll
    for (int i = 0; i < 16; ++i) n += fw[i];
    cs[t] = (ncs + EPS) / (n + (float)K * EPS) * n;
}

// ---- counting-sort scatter ----
__global__ void k_scatter(const int* __restrict__ am, const int* __restrict__ offsets,
                          int* __restrict__ cursor, int* __restrict__ sorted,
                          int* __restrict__ sortedk) {
    const int b = blockIdx.x * blockDim.x + threadIdx.x;
    const int k = am[b];
    const int pos = atomicAdd(&cursor[k], 1);
    sorted[offsets[k] + pos] = b;
    sortedk[offsets[k] + pos] = k;
}

// ---- balanced segmented reduction: 64 sorted rows per block ----
__launch_bounds__(512)
__global__ void k_segred(const float* __restrict__ x, const int* __restrict__ sorted,
                         const int* __restrict__ sortedk, float* __restrict__ esum) {
    __shared__ int srow[SEG];
    __shared__ int skid[SEG];
    const int b = blockIdx.x;
    const int t = threadIdx.x;
    if (t < SEG) {
        srow[t] = sorted[b * SEG + t];
        skid[t] = sortedk[b * SEG + t];
    }
    __syncthreads();

    float a = 0.f;
    int cur = skid[0];
#pragma unroll 8
    for (int i = 0; i < SEG; ++i) {
        const int k = skid[i];
        if (k != cur) {
            atomicAdd(&esum[(size_t)cur * VEC + t], a);
            a = 0.f;
            cur = k;
        }
        a += x[(size_t)srow[i] * VEC + t];
    }
    atomicAdd(&esum[(size_t)cur * VEC + t], a);
}

// ---- finalize: transpose esum (K,VEC)->(VEC,K), EMA + normalize ----
__launch_bounds__(256)
__global__ void k_finalize(const float* __restrict__ esum, const float* __restrict__ embed_avg,
                           const float* __restrict__ cs, float* __restrict__ out) {
    __shared__ float tile[64][65];
    const int k0 = blockIdx.x * 64;
    const int v0 = blockIdx.y * 64;
    const int c = threadIdx.x & 63;
    const int r0 = threadIdx.x >> 6;
#pragma unroll
    for (int j = 0; j < 16; ++j) {
        const int r = r0 + j * 4;
        tile[r][c] = esum[(size_t)(k0 + r) * VEC + v0 + c];
    }
    __syncthreads();
    const float csk = cs[k0 + c];
#pragma unroll
    for (int j = 0; j < 16; ++j) {
        const int r = r0 + j * 4;
        const size_t o = (size_t)(v0 + r) * K + k0 + c;
        out[o] = (GAMMA * embed_avg[o] + (1.0f - GAMMA) * tile[c][r]) / csk;
    }
}

extern "C" void kernel_launch(void* const* d_in, const int* in_sizes, int n_in,
                              void* d_out, int out_size, void* d_ws, size_t ws_size,
                              hipStream_t stream) {
    const float* x            = (const float*)d_in[0];   // (BATCH, VEC)
    const float* w            = (const float*)d_in[1];   // (VEC, K)
    const float* cluster_size = (const float*)d_in[2];   // (K,)
    const float* embed_avg    = (const float*)d_in[3];   // (VEC, K)
    float* out = (float*)d_out;                          // (VEC, K)

    // ws layout (~87 MB)
    u64*   keysA   = (u64*)d_ws;                          // 16 x BATCH
    u64*   keysB   = keysA + (size_t)16 * BATCH;          // 16 x BATCH
    int*   am      = (int*)(keysB + (size_t)16 * BATCH);  // BATCH
    u64*   list    = (u64*)(am + BATCH);                  // BATCH
    float* w2p     = (float*)(list + BATCH);              // 8 x K
    float* cs      = w2p + 8 * K;                         // K
    int*   cc      = (int*)(cs + K);                      // counts K | cursor K | listcnt (+pad)
    int*   counts  = cc;
    int*   cursor  = cc + K;
    int*   listcnt = cc + 2 * K;
    int*   offsets = cc + 2 * K + 64;                     // K
    int*   sorted  = offsets + K;                         // BATCH
    int*   sortedk = sorted + BATCH;                      // BATCH
    float* esum    = (float*)(sortedk + BATCH);           // (K, VEC), 2 MB
    us8*   wpk     = (us8*)(esum + (size_t)K * VEC);      // 1 MB (32 x 2048 granules)
    float* wT      = (float*)(wpk + (size_t)32 * TG);     // (K, VEC), 2 MB
    us8*   xpk     = (us8*)(wT + (size_t)K * VEC);        // 64 MB (2048 x 2048 granules)

    k_pack_w<<<32, 256, 0, stream>>>(w, wpk, wT, w2p, cc);
    k_pack_x<<<2048, 256, 0, stream>>>(x, xpk);
    k_gemm<<<1024, 512, 0, stream>>>(xpk, wpk, w2p, keysA, keysB);
    k_verify<<<BATCH / 256, 256, 0, stream>>>(keysA, keysB, am, counts, list, listcnt, esum);
    k_recheck<<<256, 256, 0, stream>>>(x, wT, w2p, list, listcnt, am, counts);
    k_scan<<<1, K, 0, stream>>>(counts, cluster_size, offsets, cs);
    k_scatter<<<BATCH / 256, 256, 0, stream>>>(am, offsets, cursor, sorted, sortedk);
    k_segred<<<BATCH / SEG, 512, 0, stream>>>(x, sorted, sortedk, esum);
    k_finalize<<<dim3(K / 64, VEC / 64), 256, 0, stream>>>(esum, embed_avg, cs, out);
}

// Round 16
// 407.236 us; speedup vs baseline: 1.0708x; 1.0162x over previous
//
#include <hip/hip_runtime.h>

typedef unsigned int uint;
typedef unsigned short ushort_t;
typedef unsigned long long u64;
typedef __attribute__((ext_vector_type(4))) float f32x4;
typedef __attribute__((ext_vector_type(8))) __bf16 bf16x8;
typedef __attribute__((ext_vector_type(8))) unsigned short us8;

#define BATCH 65536
#define VEC 512
#define K 1024
#define GAMMA 0.99f
#define EPS 1e-05f
#define SEG 64
#define MARGIN 0.75f

// GEMM geometry: 256x256 tile, BK=64, 8 waves (2M x 4N), per-wave 128x64
#define NKT (VEC / 64)      // 8 K-tiles
#define TG 2048             // granules per K-tile per operand

// round-to-nearest-even f32 -> bf16
__device__ __forceinline__ ushort_t rtn(float f) {
    uint u = __float_as_uint(f);
    return (ushort_t)((u + 0x7FFFu + ((u >> 16) & 1u)) >> 16);
}

__device__ __forceinline__ void gl16(const void* g, void* l) {
    __builtin_amdgcn_global_load_lds(
        (const __attribute__((address_space(1))) unsigned int*)g,
        (__attribute__((address_space(3))) unsigned int*)l, 16, 0, 0);
}

__device__ __forceinline__ float dec_key(uint e) {
    uint b = (e & 0x80000000u) ? (e & 0x7FFFFFFFu) : ~e;
    return __uint_as_float(b);
}

#define BC8(p) __builtin_bit_cast(bf16x8, (p))

// ---- merged pack: blocks 0..31 = w-pack (+wT, w2p, cc init); 32..2079 = x-pack
// B granule g = ct*128 + ksub*64 + lane: col = gx*256+ct*16+(lane&15),
//   k = kt*64 + ksub*32 + (lane>>4)*8 + j.  A granules identical with rows.
__global__ void k_pack(const float* __restrict__ w, const float* __restrict__ x,
                       us8* __restrict__ wpk, us8* __restrict__ xpk,
                       float* __restrict__ wT, float* __restrict__ w2p,
                       int* __restrict__ cc /* counts|cursor: 2048 ints */) {
    __shared__ float lds[32][257];
    const int b = blockIdx.x;
    const int t = threadIdx.x;

    if (b < 32) {
        const int gx = b >> 3, kt = b & 7;
        float s = 0.f;
#pragma unroll
        for (int ih = 0; ih < 2; ++ih) {
            __syncthreads();
#pragma unroll
            for (int r = 0; r < 32; ++r)
                lds[r][t] = w[(size_t)(kt * 64 + ih * 32 + r) * K + gx * 256 + t];
            __syncthreads();

#pragma unroll
            for (int r = 0; r < 32; ++r) { float f = lds[r][t]; s += f * f; }

#pragma unroll
            for (int i = 0; i < 4; ++i) {
                const int c = i * 256 + t;
                const int ct = c >> 6, lane = c & 63;
                const int cl = ct * 16 + (lane & 15);
                const int r0 = (lane >> 4) * 8;
                us8 v;
#pragma unroll
                for (int j = 0; j < 8; ++j) v[j] = rtn(lds[r0 + j][cl]);
                wpk[(size_t)b * TG + ct * 128 + ih * 64 + lane] = v;
            }

#pragma unroll
            for (int rr = 0; rr < 8; ++rr) {
                f32x4 v = {lds[rr * 4 + 0][t], lds[rr * 4 + 1][t],
                           lds[rr * 4 + 2][t], lds[rr * 4 + 3][t]};
                *(f32x4*)&wT[(size_t)(gx * 256 + t) * VEC + kt * 64 + ih * 32 + rr * 4] = v;
            }
        }
        w2p[kt * K + gx * 256 + t] = s;
        if (b < 8) cc[b * 256 + t] = 0;
    } else {
        const int blk = b - 32;              // 0..2047: gy*8 + kt
        const int gy = blk >> 3, kt = blk & 7;
#pragma unroll
        for (int i = 0; i < 8; ++i) {
            const int g = i * 256 + t;
            const int slab = g >> 7, ksub = (g >> 6) & 1, lane = g & 63;
            const int row = gy * 256 + slab * 16 + (lane & 15);
            const int k = kt * 64 + ksub * 32 + ((lane >> 4) << 3);
            const f32x4 q0 = *(const f32x4*)&x[(size_t)row * VEC + k];
            const f32x4 q1 = *(const f32x4*)&x[(size_t)row * VEC + k + 4];
            us8 v;
#pragma unroll
            for (int j = 0; j < 4; ++j) { v[j] = rtn(q0[j]); v[4 + j] = rtn(q1[j]); }
            xpk[(size_t)blk * TG + g] = v;
        }
    }
}

// ---- main: 256x256 BK=64 MFMA distance GEMM, 2 phases/K-tile, counted vmcnt
// 1024 blocks x 512 thr; 1 block/CU (128KB LDS). Top-2 per row per slot.
__launch_bounds__(512, 2)
__global__ void k_gemm(const us8* __restrict__ xpk, const us8* __restrict__ wpk,
                       const float* __restrict__ w2p,
                       u64* __restrict__ keysA, u64* __restrict__ keysB) {
    __shared__ us8 lds[2][2 * TG];   // [0..2047]=A, [2048..4095]=B; 128 KB

    const int blk = blockIdx.x;
    // XCD-chunked bijection (1024 % 8 == 0)
    const int ord = blk >> 3;
    const int gy = (blk & 7) * 32 + (ord >> 2);
    const int gx = ord & 3;
    const int t = threadIdx.x;
    const int lane = t & 63;
    const int wv = t >> 6;
    const int wm = wv >> 2;      // 0..1 (128 rows)
    const int wn = wv & 3;       // 0..3 (64 cols)

    const us8* asrc = xpk + (size_t)gy * (NKT * TG);
    const us8* bsrc = wpk + (size_t)gx * (NKT * TG);

    auto stage = [&](int slot, int kt) {
        const us8* sa = asrc + (size_t)kt * TG;
        const us8* sb = bsrc + (size_t)kt * TG;
#pragma unroll
        for (int i = 0; i < 4; ++i) gl16(sa + i * 512 + t, &lds[slot][i * 512 + t]);
#pragma unroll
        for (int i = 0; i < 4; ++i) gl16(sb + i * 512 + t, &lds[slot][TG + i * 512 + t]);
    };

    f32x4 acc[8][4];
#pragma unroll
    for (int i = 0; i < 8; ++i)
#pragma unroll
        for (int j = 0; j < 4; ++j) acc[i][j] = (f32x4){0.f, 0.f, 0.f, 0.f};

    stage(0, 0);
    stage(1, 1);

    for (int kt = 0; kt < NKT; ++kt) {
        const int buf = kt & 1;
        if (kt + 1 < NKT) {
            if (kt >= 1) stage(buf ^ 1, kt + 1);   // slot freed at end of kt-1
            asm volatile("s_waitcnt vmcnt(8)" ::: "memory");  // tile kt landed
        } else {
            asm volatile("s_waitcnt vmcnt(0)" ::: "memory");
        }
        __builtin_amdgcn_s_barrier();     // all waves' staging of tile kt visible

#pragma unroll
        for (int ph = 0; ph < 2; ++ph) {
            const int kb = ph * 64;       // ksub offset within granule row
            bf16x8 ah[8], bh[4];
#pragma unroll
            for (int rt = 0; rt < 8; ++rt)
                ah[rt] = BC8(lds[buf][(wm * 8 + rt) * 128 + kb + lane]);
#pragma unroll
            for (int ct = 0; ct < 4; ++ct)
                bh[ct] = BC8(lds[buf][TG + (wn * 4 + ct) * 128 + kb + lane]);
            __builtin_amdgcn_s_barrier();
            asm volatile("s_waitcnt lgkmcnt(0)" ::: "memory");
            __builtin_amdgcn_sched_barrier(0);
            __builtin_amdgcn_s_setprio(1);
#pragma unroll
            for (int rt = 0; rt < 8; ++rt)
#pragma unroll
                for (int ct = 0; ct < 4; ++ct)
                    acc[rt][ct] = __builtin_amdgcn_mfma_f32_16x16x32_bf16(ah[rt], bh[ct], acc[rt][ct], 0, 0, 0);
            __builtin_amdgcn_s_setprio(0);
            __builtin_amdgcn_s_barrier();
        }
    }

    // epilogue: dist = w2 - 2*dot; per-row TOP-2 over wave's 64 cols; slot store
    const int col_base = gx * 256 + wn * 64;
    float w2c[4];
#pragma unroll
    for (int ct = 0; ct < 4; ++ct) {
        const int col = col_base + ct * 16 + (lane & 15);
        float s = 0.f;
#pragma unroll
        for (int p = 0; p < 8; ++p) s += w2p[p * K + col];
        w2c[ct] = s;
    }
    const int slot = gx * 4 + wn;

#pragma unroll
    for (int rt = 0; rt < 8; ++rt) {
#pragma unroll
        for (int reg = 0; reg < 4; ++reg) {
            u64 k1 = ~0ull, k2 = ~0ull;
#pragma unroll
            for (int ct = 0; ct < 4; ++ct) {
                float dist = w2c[ct] - 2.0f * acc[rt][ct][reg];
                uint su = __float_as_uint(dist);
                su = (su & 0x80000000u) ? ~su : (su | 0x80000000u);
                const u64 key = ((u64)su << 32) | (uint)(col_base + ct * 16 + (lane & 15));
                if (key < k1) { k2 = k1; k1 = key; }
                else if (key < k2) { k2 = key; }
            }
#pragma unroll
            for (int m = 1; m < 16; m <<= 1) {
                u64 o1 = __shfl_xor((unsigned long long)k1, m);
                u64 o2 = __shfl_xor((unsigned long long)k2, m);
                u64 lo = k1 < o1 ? k1 : o1;
                u64 hi = k1 < o1 ? o1 : k1;
                u64 mn2 = k2 < o2 ? k2 : o2;
                k1 = lo;
                k2 = hi < mn2 ? hi : mn2;
            }
            if ((lane & 15) == 0) {
                const int row = gy * 256 + wm * 128 + rt * 16 + (lane >> 4) * 4 + reg;
                keysA[(size_t)slot * BATCH + row] = k1;
                keysB[(size_t)slot * BATCH + row] = k2;
            }
        }
    }
}

// ---- verify + fused recheck: merge 16 slots -> top-2; margin; exact recheck
//      of marginal rows via block-local LDS list (wave-cooperative). Also
//      zeroes esum. ----
__global__ void k_verify(const u64* __restrict__ keysA, const u64* __restrict__ keysB,
                         const float* __restrict__ x, const float* __restrict__ wT,
                         const float* __restrict__ w2p,
                         int* __restrict__ am, int* __restrict__ counts,
                         float* __restrict__ esum) {
    __shared__ int lrow[256];
    __shared__ int lcc[256];
    __shared__ int lcnt;
    const int t = threadIdx.x;
    const int r = blockIdx.x * 256 + t;
    const int lane = t & 63;

    if (t == 0) lcnt = 0;
    __syncthreads();

    f32x4 z = {0.f, 0.f, 0.f, 0.f};
    ((f32x4*)esum)[r * 2] = z;
    ((f32x4*)esum)[r * 2 + 1] = z;

    u64 m1 = ~0ull, s = ~0ull;
    int i1 = 0;
#pragma unroll
    for (int i = 0; i < 16; ++i) {
        u64 a = keysA[(size_t)i * BATCH + r];
        if (a < m1) { s = m1; m1 = a; i1 = i; }
        else if (a < s) s = a;
    }
    u64 b = keysB[(size_t)i1 * BATCH + r];
    u64 m2 = s < b ? s : b;

    const float d1 = dec_key((uint)(m1 >> 32));
    const float d2 = dec_key((uint)(m2 >> 32));
    const int c1 = (int)(uint)m1 & 1023;
    const int c2 = (int)(uint)m2 & 1023;

    if (d2 - d1 > MARGIN) {
        am[r] = c1;
        atomicAdd(&counts[c1], 1);
    } else {
        int p = atomicAdd(&lcnt, 1);
        lrow[p] = r;
        lcc[p] = (c1 << 10) | c2;
    }
    __syncthreads();

    const int n = lcnt;
    for (int idx = t >> 6; idx < n; idx += 4) {
        const int r2 = lrow[idx];
        const int cc1 = lcc[idx] >> 10;
        const int cc2 = lcc[idx] & 1023;
        const f32x4 x0 = *(const f32x4*)&x[(size_t)r2 * VEC + lane * 8];
        const f32x4 x1 = *(const f32x4*)&x[(size_t)r2 * VEC + lane * 8 + 4];
        float d[2];
        const int cand[2] = {cc1, cc2};
#pragma unroll
        for (int j = 0; j < 2; ++j) {
            const int c = cand[j];
            const f32x4 w0 = *(const f32x4*)&wT[(size_t)c * VEC + lane * 8];
            const f32x4 w1 = *(const f32x4*)&wT[(size_t)c * VEC + lane * 8 + 4];
            float p = x0[0] * w0[0] + x0[1] * w0[1] + x0[2] * w0[2] + x0[3] * w0[3]
                    + x1[0] * w1[0] + x1[1] * w1[1] + x1[2] * w1[2] + x1[3] * w1[3];
#pragma unroll
            for (int m = 1; m < 64; m <<= 1) p += __shfl_xor(p, m);
            float w2 = 0.f;
#pragma unroll
            for (int q = 0; q < 8; ++q) w2 += w2p[q * K + c];
            d[j] = w2 - 2.0f * p;
        }
        const int win = (d[0] < d[1] || (d[0] == d[1] && cc1 < cc2)) ? cc1 : cc2;
        if (lane == 0) {
            am[r2] = win;
            atomicAdd(&counts[win], 1);
        }
    }
}

// ---- scatter with inline (redundant, deterministic) exclusive scan ----
// 64 blocks x 1024 thr; every block computes the same global scan of counts.
__launch_bounds__(1024)
__global__ void k_scatter(const int* __restrict__ counts, const int* __restrict__ am,
                          int* __restrict__ cursor, int* __restrict__ sorted,
                          int* __restrict__ sortedk) {
    __shared__ int soff[K];
    __shared__ int wsum[16];
    const int t = threadIdx.x;
    const int lane = t & 63, wid = t >> 6;

    const int c = counts[t];
    int s = c;
#pragma unroll
    for (int d = 1; d < 64; d <<= 1) {
        int o = __shfl_up(s, d);
        if (lane >= d) s += o;
    }
    if (lane == 63) wsum[wid] = s;
    __syncthreads();
    if (wid == 0 && lane < 16) {
        int v = wsum[lane];
#pragma unroll
        for (int d = 1; d < 16; d <<= 1) {
            int o = __shfl_up(v, d);
            if (lane >= d) v += o;
        }
        wsum[lane] = v;
    }
    __syncthreads();
    soff[t] = (wid ? wsum[wid - 1] : 0) + s - c;
    __syncthreads();

    const int r = blockIdx.x * 1024 + t;
    const int k = am[r];
    const int pos = atomicAdd(&cursor[k], 1);
    sorted[soff[k] + pos] = r;
    sortedk[soff[k] + pos] = k;
}

// ---- balanced segmented reduction: 64 sorted rows per block ----
__launch_bounds__(512)
__global__ void k_segred(const float* __restrict__ x, const int* __restrict__ sorted,
                         const int* __restrict__ sortedk, float* __restrict__ esum) {
    __shared__ int srow[SEG];
    __shared__ int skid[SEG];
    const int b = blockIdx.x;
    const int t = threadIdx.x;
    if (t < SEG) {
        srow[t] = sorted[b * SEG + t];
        skid[t] = sortedk[b * SEG + t];
    }
    __syncthreads();

    float a = 0.f;
    int cur = skid[0];
#pragma unroll 8
    for (int i = 0; i < SEG; ++i) {
        const int k = skid[i];
        if (k != cur) {
            atomicAdd(&esum[(size_t)cur * VEC + t], a);
            a = 0.f;
            cur = k;
        }
        a += x[(size_t)srow[i] * VEC + t];
    }
    atomicAdd(&esum[(size_t)cur * VEC + t], a);
}

// ---- finalize: inline cs computation + transpose + EMA + normalize ----
// Every block redundantly computes n (identical FP order -> deterministic).
__launch_bounds__(256)
__global__ void k_finalize(const float* __restrict__ esum, const float* __restrict__ embed_avg,
                           const int* __restrict__ counts,
                           const float* __restrict__ cluster_size,
                           float* __restrict__ out) {
    __shared__ float tile[64][65];
    __shared__ float wred[4];
    const int t = threadIdx.x;
    const int k0 = blockIdx.x * 64;
    const int v0 = blockIdx.y * 64;
    const int c = t & 63;
    const int r0 = t >> 6;
    const int lane = t & 63, wid = t >> 6;

    // n = sum over all K of ncs (fixed order: thread j owns clusters 4j..4j+3)
    float part = 0.f;
#pragma unroll
    for (int j = 0; j < 4; ++j) {
        const int idx = t * 4 + j;
        const int cv = counts[idx];
        part += GAMMA * cluster_size[idx] + (1.0f - GAMMA) * ((cv == 0) ? 1.0f : (float)cv);
    }
#pragma unroll
    for (int d = 32; d > 0; d >>= 1) part += __shfl_xor(part, d);
    if (lane == 0) wred[wid] = part;

#pragma unroll
    for (int j = 0; j < 16; ++j) {
        const int r = r0 + j * 4;
        tile[r][c] = esum[(size_t)(k0 + r) * VEC + v0 + c];
    }
    __syncthreads();

    const float n = (wred[0] + wred[1]) + (wred[2] + wred[3]);
    const int kc = k0 + c;
    const int cv = counts[kc];
    const float ncs = GAMMA * cluster_size[kc] + (1.0f - GAMMA) * ((cv == 0) ? 1.0f : (float)cv);
    const float csk = (ncs + EPS) / (n + (float)K * EPS) * n;

#pragma unroll
    for (int j = 0; j < 16; ++j) {
        const int r = r0 + j * 4;
        const size_t o = (size_t)(v0 + r) * K + k0 + c;
        out[o] = (GAMMA * embed_avg[o] + (1.0f - GAMMA) * tile[c][r]) / csk;
    }
}

extern "C" void kernel_launch(void* const* d_in, const int* in_sizes, int n_in,
                              void* d_out, int out_size, void* d_ws, size_t ws_size,
                              hipStream_t stream) {
    const float* x            = (const float*)d_in[0];   // (BATCH, VEC)
    const float* w            = (const float*)d_in[1];   // (VEC, K)
    const float* cluster_size = (const float*)d_in[2];   // (K,)
    const float* embed_avg    = (const float*)d_in[3];   // (VEC, K)
    float* out = (float*)d_out;                          // (VEC, K)

    // ws layout (~86 MB)
    u64*   keysA   = (u64*)d_ws;                          // 16 x BATCH
    u64*   keysB   = keysA + (size_t)16 * BATCH;          // 16 x BATCH
    int*   am      = (int*)(keysB + (size_t)16 * BATCH);  // BATCH
    float* w2p     = (float*)(am + BATCH);                // 8 x K
    int*   cc      = (int*)(w2p + 8 * K);                 // counts K | cursor K
    int*   counts  = cc;
    int*   cursor  = cc + K;
    int*   sorted  = cc + 2 * K;                          // BATCH
    int*   sortedk = sorted + BATCH;                      // BATCH
    float* esum    = (float*)(sortedk + BATCH);           // (K, VEC), 2 MB
    us8*   wpk     = (us8*)(esum + (size_t)K * VEC);      // 1 MB (32 x 2048)
    float* wT      = (float*)(wpk + (size_t)32 * TG);     // (K, VEC), 2 MB
    us8*   xpk     = (us8*)(wT + (size_t)K * VEC);        // 64 MB (2048 x 2048)

    k_pack<<<2080, 256, 0, stream>>>(w, x, wpk, xpk, wT, w2p, cc);
    k_gemm<<<1024, 512, 0, stream>>>(xpk, wpk, w2p, keysA, keysB);
    k_verify<<<BATCH / 256, 256, 0, stream>>>(keysA, keysB, x, wT, w2p, am, counts, esum);
    k_scatter<<<64, 1024, 0, stream>>>(counts, am, cursor, sorted, sortedk);
    k_segred<<<BATCH / SEG, 512, 0, stream>>>(x, sorted, sortedk, esum);
    k_finalize<<<dim3(K / 64, VEC / 64), 256, 0, stream>>>(esum, embed_avg, counts, cluster_size, out);
}